// Round 11
// baseline (13355.249 us; speedup 1.0000x reference)
//
#include <hip/hip_runtime.h>
#include <hip/hip_bf16.h>

// ---------------------------------------------------------------------------
// CompositePulseTransformerDecoder — MI355X (gfx950), round 11
// PARALLEL GROUP PIPELINES: 96 blocks = 12 layers x 8 groups, 512 threads.
// Block (l,g) runs layer l for batch group g (16 rows). The 8 groups are
// independent pipelines -> makespan = (16 tokens + 11 fill) x T_hop = 27 hops
// (vs 139 in r8-r10 which serialized groups inside each layer block).
// Body: r7's proven full-layer 512-thread phases (2-bank weight prefetch).
// Protocol: r10's proven fence-free parity-xh + fin counters, per (l,g).
// XCD map: bid%8 == l%8 -> each layer's 1.57MB weights L2-resident (<=2
// layers/XCD). 32 filler blocks (grid 128) exit immediately.
// ---------------------------------------------------------------------------

typedef __attribute__((ext_vector_type(8))) short short8;
typedef __attribute__((ext_vector_type(4))) float f32x4;

#define EPS_ 1e-5f

__device__ __forceinline__ unsigned short f2b(float x){
  union { float f; unsigned u; } c; c.f = x;
  unsigned r = (c.u + 0x7fffu + ((c.u >> 16) & 1u)) >> 16;
  return (unsigned short)r;
}
__device__ __forceinline__ float b2f(unsigned short u){
  union { unsigned u; float f; } c; c.u = ((unsigned)u) << 16;
  return c.f;
}
__device__ __forceinline__ unsigned long long pack2f(float a, float b){
  union { float f; unsigned u; } x, y; x.f = a; y.f = b;
  return (unsigned long long)x.u | ((unsigned long long)y.u << 32);
}
__device__ __forceinline__ float lo_f(unsigned long long v){
  union { unsigned u; float f; } c; c.u = (unsigned)v; return c.f;
}
__device__ __forceinline__ float hi_f(unsigned long long v){
  union { unsigned u; float f; } c; c.u = (unsigned)(v >> 32); return c.f;
}

#define AL(p)    __hip_atomic_load((p),  __ATOMIC_RELAXED, __HIP_MEMORY_SCOPE_AGENT)
#define AS(p,v)  __hip_atomic_store((p), (v), __ATOMIC_RELAXED, __HIP_MEMORY_SCOPE_AGENT)

// ws layout (bytes) — total 45,220,352 (< 45,744,128 proven)
#define OFF_WQKV 0ull            // 12*768*256  bf16 = 4,718,592
#define OFF_WO   4718592ull      // 12*256*256  bf16 = 1,572,864
#define OFF_L1   6291456ull      // 12*1024*256 bf16 = 6,291,456
#define OFF_L2   12582912ull     // 12*256*1024 bf16 = 6,291,456
#define OFF_SRC  18874368ull     // 128*256 f32 = 131,072
#define OFF_CC   19005440ull     // 12*128*256 bf16 = 786,432
#define OFF_KV   19791872ull     // [12][8g*16row][4h][16t][128] bf16 = 25,165,824
#define OFF_XH   44957696ull     // [2][8][16][128] u64 (f32 pairs) = 262,144
#define OFF_FLG  45219840ull     // fin[12][8] ints (+pad) = 512

// ---------------- weight f32 -> bf16 conversion --------------------------
__global__ void k_conv(const float* __restrict__ wqkv, const float* __restrict__ wo,
                       const float* __restrict__ l1, const float* __restrict__ l2,
                       unsigned short* __restrict__ dst){
  const long long n0 = 12LL*768*256;
  const long long n1 = n0 + 12LL*256*256;
  const long long n2 = n1 + 12LL*1024*256;
  const long long n3 = n2 + 12LL*256*1024;
  for (long long idx = (long long)blockIdx.x*256 + threadIdx.x; idx < n3;
       idx += (long long)gridDim.x*256){
    float v;
    if (idx < n0) v = wqkv[idx];
    else if (idx < n1) v = wo[idx - n0];
    else if (idx < n2) v = l1[idx - n1];
    else v = l2[idx - n2];
    dst[idx] = f2b(v);
  }
}

// -------- src = vec @ tok_W.T + tok_b ;  prime xh parity-0 ---------------
__global__ void k_src(const float* __restrict__ U_real, const float* __restrict__ U_imag,
                      const float* __restrict__ tok_W, const float* __restrict__ tok_b,
                      const float* __restrict__ pos,
                      float* __restrict__ src, float* __restrict__ xh0){
  int b = blockIdx.x, n = threadIdx.x;
  const float* w = tok_W + n*128;
  const float* ur = U_real + b*64;
  const float* ui = U_imag + b*64;
  float acc = tok_b[n];
  #pragma unroll 8
  for (int k = 0; k < 64; ++k) acc += w[k]*ur[k];
  #pragma unroll 8
  for (int k = 0; k < 64; ++k) acc += w[64+k]*ui[k];
  src[b*256+n] = acc;               // raw src (for k_cc)
  xh0[b*256+n] = acc + pos[n];      // token-0 input = src + pos[0]
}

// ------- cross-attn constant: cc[l][b] = Wo_ca @ (Wv_ca@src_b + bv) + bo --
__global__ void k_cc(const float* __restrict__ caW, const float* __restrict__ cab,
                     const float* __restrict__ caWo, const float* __restrict__ cabo,
                     const float* __restrict__ src, unsigned short* __restrict__ cc){
  int l = blockIdx.x >> 7, b = blockIdx.x & 127, t = threadIdx.x;
  __shared__ float v[256];
  const float* s = src + b*256;
  {
    const float* w = caW + ((long long)l*768 + 512 + t)*256;
    float a = cab[l*768 + 512 + t];
    #pragma unroll 8
    for (int k = 0; k < 256; ++k) a += w[k]*s[k];
    v[t] = a;
  }
  __syncthreads();
  {
    const float* w = caWo + ((long long)l*256 + t)*256;
    float a = cabo[l*256 + t];
    #pragma unroll 8
    for (int k = 0; k < 256; ++k) a += w[k]*v[k];
    cc[((long long)l*128 + b)*256 + t] = f2b(a);
  }
}

// ---------------- main kernel: block (l, grp) ----------------------------
__global__ __launch_bounds__(512, 1) void k_main(
  const unsigned short* __restrict__ wqkv,   // [12][768][256] bf16
  const unsigned short* __restrict__ wo,     // [12][256][256]
  const unsigned short* __restrict__ wl1,    // [12][1024][256]
  const unsigned short* __restrict__ wl2,    // [12][256][1024]
  const float* __restrict__ bqkv, const float* __restrict__ bo_,
  const float* __restrict__ bl1,  const float* __restrict__ bl2,
  const float* __restrict__ g1, const float* __restrict__ be1,
  const float* __restrict__ g2, const float* __restrict__ be2,
  const float* __restrict__ g3, const float* __restrict__ be3,
  const unsigned short* __restrict__ cc,     // [12][128][256] bf16
  const float* __restrict__ pos,             // [17][256]
  const float* __restrict__ outW,            // [4][256]
  const float* __restrict__ outb,
  const float* __restrict__ plow, const float* __restrict__ phigh,
  unsigned short* __restrict__ kvc,          // [12][8*16][4][16][128] bf16
  unsigned long long* __restrict__ xh,       // [2][8][16][128] u64 (f32 pairs)
  int* __restrict__ flags,                   // fin[12][8]
  float* __restrict__ out)                   // [128][16][4]
{
  __shared__ float xf[16][260];            // residual x (f32)
  __shared__ float zf[16][260];            // pre-LN scratch
  __shared__ float yf[16][260];            // post-LN2 (FFN residual)
  __shared__ unsigned short xb[16][264];   // bf16 A-operand (x / y)
  __shared__ unsigned short qs[16][264];   // q full 256
  __shared__ unsigned short os[16][264];   // attn out full 256
  __shared__ unsigned short hb[16][1048];  // relu(lin1) full 1024

  const int tid  = threadIdx.x;
  const int w    = tid >> 6, lane = tid & 63;
  const int mrow = lane & 15, kgrp = lane >> 4;

  // bid -> (layer, group): XCD(bid%8) == l%8 (weights L2-resident per XCD)
  const int xcd   = blockIdx.x & 7;
  const int inner = blockIdx.x >> 3;       // 0..15
  const int grp   = inner & 7;
  const int lh    = inner >> 3;            // 0,1
  const int l     = xcd + 8*lh;
  if (l > 11) return;                      // 32 filler blocks exit
  const int prev  = (l == 0) ? 11 : (l-1);

  const unsigned short* wqkv_l = wqkv + (size_t)l*196608;
  const unsigned short* wo_l   = wo   + (size_t)l*65536;
  const unsigned short* wl1_l  = wl1  + (size_t)l*262144;
  const unsigned short* wl2_l  = wl2  + (size_t)l*262144;
  unsigned short* kvc_l        = kvc  + (size_t)l*1048576;
  int* fin = flags;                        // [12][8]

  for (int t = 0; t < 16; ++t){
    // ===== prefetch QKV bank-0 weights (independent of input) =====
    short8 b0[8], b1[8];
    {
      const unsigned short* p0 = wqkv_l + ((size_t)(w*16 + mrow))*256 + kgrp*8;
      #pragma unroll
      for (int kc = 0; kc < 8; ++kc) b0[kc] = *(const short8*)(p0 + kc*32);
    }
    // ===== wait upstream (1 flag), gather xh[l%2][grp] =====
    {
      int need = (l == 0) ? t : (t+1);
      if (need > 0 && tid == 0){
        const int* fp = fin + prev*8 + grp;
        while (AL(fp) < need) __builtin_amdgcn_s_sleep(1);
      }
      __syncthreads();
      int row = tid >> 5, c8 = (tid & 31)*8;
      const unsigned long long* xp =
          xh + ((size_t)(l & 1)*8 + grp)*2048 + (size_t)row*128 + (c8 >> 1);
      #pragma unroll
      for (int j = 0; j < 4; ++j){
        unsigned long long v = AL(xp + j);
        float f0 = lo_f(v), f1 = hi_f(v);
        xf[row][c8+2*j]   = f0;  xf[row][c8+2*j+1] = f1;
        xb[row][c8+2*j]   = f2b(f0);
        xb[row][c8+2*j+1] = f2b(f1);
      }
    }
    __syncthreads();

    // ===== QKV: 48 n-tiles, 6 per wave, 2-bank pipelined =====
    {
      short8 a[8];
      #pragma unroll
      for (int kc = 0; kc < 8; ++kc)
        a[kc] = *(const short8*)&xb[mrow][kc*32 + kgrp*8];
      #pragma unroll
      for (int j = 0; j < 6; ++j){
        if (j < 5){
          const unsigned short* pn =
              wqkv_l + ((size_t)((w + 8*(j+1))*16 + mrow))*256 + kgrp*8;
          #pragma unroll
          for (int kc = 0; kc < 8; ++kc){
            short8 v = *(const short8*)(pn + kc*32);
            if (j & 1) b0[kc] = v; else b1[kc] = v;
          }
        }
        int n_g = (w + 8*j)*16 + mrow;
        float bias = bqkv[l*768 + n_g];
        f32x4 acc = {0,0,0,0};
        #pragma unroll
        for (int kc = 0; kc < 8; ++kc)
          acc = __builtin_amdgcn_mfma_f32_16x16x32_bf16(
              a[kc], (j & 1) ? b1[kc] : b0[kc], acc, 0,0,0);
        int p = n_g >> 8, rem = n_g & 255;
        #pragma unroll
        for (int r = 0; r < 4; ++r){
          int br = kgrp*4 + r;
          float v = acc[r] + bias;
          if (p == 0){
            qs[br][rem] = f2b(v);
          } else {
            int head = rem >> 6, nl = rem & 63;
            kvc_l[(((size_t)(grp*16+br)*4 + head)*16 + t)*128
                  + (p == 2 ? 64 : 0) + nl] = f2b(v);
          }
        }
      }
    }
    __syncthreads();

    // ===== attention: 64 (row,head) tasks, 16 lanes each, 2 reps =====
    {
      #pragma unroll
      for (int rep = 0; rep < 2; ++rep){
        int task = w*8 + rep*4 + (lane >> 4);
        int row = task & 15, head = task >> 4;
        int lid = lane & 15;
        float q4[4];
        #pragma unroll
        for (int u = 0; u < 4; ++u) q4[u] = b2f(qs[row][head*64 + lid*4 + u]);
        const unsigned short* base =
            kvc_l + (((size_t)(grp*16+row)*4 + head)*16)*128 + lid*4;
        float sv[16];
        #pragma unroll
        for (int j = 0; j < 16; ++j){
          if (j <= t){
            const unsigned short* kp = base + j*128;
            float p = 0.f;
            #pragma unroll
            for (int u = 0; u < 4; ++u) p += q4[u]*b2f(kp[u]);
            p += __shfl_xor(p, 1);
            p += __shfl_xor(p, 2);
            p += __shfl_xor(p, 4);
            p += __shfl_xor(p, 8);
            sv[j] = p * 0.125f;               // 1/sqrt(64)
          } else sv[j] = -1e30f;
        }
        float mx = sv[0];
        #pragma unroll
        for (int j = 1; j < 16; ++j) mx = fmaxf(mx, sv[j]);
        float den = 0.f, e[16];
        #pragma unroll
        for (int j = 0; j < 16; ++j){ e[j] = __expf(sv[j]-mx); den += e[j]; }
        float rd = 1.f/den;
        float o4[4] = {0,0,0,0};
        #pragma unroll
        for (int j = 0; j < 16; ++j){
          if (j <= t){
            const unsigned short* vp = base + j*128 + 64;
            float ej = e[j];
            #pragma unroll
            for (int u = 0; u < 4; ++u) o4[u] += ej*b2f(vp[u]);
          }
        }
        #pragma unroll
        for (int u = 0; u < 4; ++u)
          os[row][head*64 + lid*4 + u] = f2b(o4[u]*rd);
      }
    }
    __syncthreads();

    // ===== Wo: 16 n-tiles, 2 per wave, pipelined; + residual -> zf =====
    {
      short8 a[8];
      #pragma unroll
      for (int kc = 0; kc < 8; ++kc)
        a[kc] = *(const short8*)&os[mrow][kc*32 + kgrp*8];
      short8 c0[8], c1[8];
      {
        const unsigned short* p0 = wo_l + ((size_t)(w*2*16 + mrow))*256 + kgrp*8;
        #pragma unroll
        for (int kc = 0; kc < 8; ++kc) c0[kc] = *(const short8*)(p0 + kc*32);
      }
      #pragma unroll
      for (int u = 0; u < 2; ++u){
        if (u < 1){
          const unsigned short* pn =
              wo_l + ((size_t)((w*2+1)*16 + mrow))*256 + kgrp*8;
          #pragma unroll
          for (int kc = 0; kc < 8; ++kc) c1[kc] = *(const short8*)(pn + kc*32);
        }
        int n_g = (w*2+u)*16 + mrow;
        float bias = bo_[l*256 + n_g];
        f32x4 acc = {0,0,0,0};
        #pragma unroll
        for (int kc = 0; kc < 8; ++kc)
          acc = __builtin_amdgcn_mfma_f32_16x16x32_bf16(
              a[kc], u ? c1[kc] : c0[kc], acc, 0,0,0);
        #pragma unroll
        for (int r = 0; r < 4; ++r){
          int br = kgrp*4 + r;
          zf[br][n_g] = acc[r] + bias + xf[br][n_g];
        }
      }
    }
    __syncthreads();

    // ===== LN1 + cc + LN2 -> yf, xb =====
    {
      int row = tid >> 5, c8 = (lane & 31)*8;
      float tt[8];
      #pragma unroll
      for (int k = 0; k < 8; ++k) tt[k] = zf[row][c8+k];
      float sm = 0, sq = 0;
      #pragma unroll
      for (int k = 0; k < 8; ++k){ sm += tt[k]; sq += tt[k]*tt[k]; }
      sm += __shfl_xor(sm,1);  sq += __shfl_xor(sq,1);
      sm += __shfl_xor(sm,2);  sq += __shfl_xor(sq,2);
      sm += __shfl_xor(sm,4);  sq += __shfl_xor(sq,4);
      sm += __shfl_xor(sm,8);  sq += __shfl_xor(sq,8);
      sm += __shfl_xor(sm,16); sq += __shfl_xor(sq,16);
      float mean = sm*(1.f/256), var = sq*(1.f/256) - mean*mean;
      float rs = rsqrtf(var + EPS_);
      const float* g1p = g1 + l*256 + c8;
      const float* b1p = be1 + l*256 + c8;
      const unsigned short* ccp = cc + ((size_t)l*128 + grp*16 + row)*256 + c8;
      #pragma unroll
      for (int k = 0; k < 8; ++k)
        tt[k] = (tt[k]-mean)*rs*g1p[k] + b1p[k] + b2f(ccp[k]);
      sm = 0; sq = 0;
      #pragma unroll
      for (int k = 0; k < 8; ++k){ sm += tt[k]; sq += tt[k]*tt[k]; }
      sm += __shfl_xor(sm,1);  sq += __shfl_xor(sq,1);
      sm += __shfl_xor(sm,2);  sq += __shfl_xor(sq,2);
      sm += __shfl_xor(sm,4);  sq += __shfl_xor(sq,4);
      sm += __shfl_xor(sm,8);  sq += __shfl_xor(sq,8);
      sm += __shfl_xor(sm,16); sq += __shfl_xor(sq,16);
      mean = sm*(1.f/256); var = sq*(1.f/256) - mean*mean;
      rs = rsqrtf(var + EPS_);
      const float* g2p = g2 + l*256 + c8;
      const float* b2p = be2 + l*256 + c8;
      #pragma unroll
      for (int k = 0; k < 8; ++k){
        float y = (tt[k]-mean)*rs*g2p[k] + b2p[k];
        yf[row][c8+k] = y;
        xb[row][c8+k] = f2b(y);
      }
    }
    __syncthreads();

    // ===== lin1: 64 n-tiles, 8 per wave, pipelined; relu -> hb =====
    {
      short8 a[8];
      #pragma unroll
      for (int kc = 0; kc < 8; ++kc)
        a[kc] = *(const short8*)&xb[mrow][kc*32 + kgrp*8];
      short8 c0[8], c1[8];
      {
        const unsigned short* p0 = wl1_l + ((size_t)(w*16 + mrow))*256 + kgrp*8;
        #pragma unroll
        for (int kc = 0; kc < 8; ++kc) c0[kc] = *(const short8*)(p0 + kc*32);
      }
      #pragma unroll
      for (int j = 0; j < 8; ++j){
        if (j < 7){
          const unsigned short* pn =
              wl1_l + ((size_t)((w + 8*(j+1))*16 + mrow))*256 + kgrp*8;
          #pragma unroll
          for (int kc = 0; kc < 8; ++kc){
            short8 v = *(const short8*)(pn + kc*32);
            if (j & 1) c0[kc] = v; else c1[kc] = v;
          }
        }
        int n_g = (w + 8*j)*16 + mrow;
        float bias = bl1[l*1024 + n_g];
        f32x4 acc = {0,0,0,0};
        #pragma unroll
        for (int kc = 0; kc < 8; ++kc)
          acc = __builtin_amdgcn_mfma_f32_16x16x32_bf16(
              a[kc], (j & 1) ? c1[kc] : c0[kc], acc, 0,0,0);
        #pragma unroll
        for (int r = 0; r < 4; ++r){
          float hv = acc[r] + bias;
          hb[kgrp*4 + r][n_g] = f2b(hv > 0.f ? hv : 0.f);
        }
      }
    }
    __syncthreads();

    // ===== lin2: 2 n-tiles/wave, K=1024 in 8 chunks, pipelined =====
    {
      short8 c0[8], c1[8];
      f32x4 acc0 = {0,0,0,0}, acc1 = {0,0,0,0};
      {
        const unsigned short* p0 = wl2_l + ((size_t)(w*2*16 + mrow))*1024 + kgrp*8;
        #pragma unroll
        for (int kc = 0; kc < 8; ++kc) c0[kc] = *(const short8*)(p0 + kc*32);
      }
      #pragma unroll
      for (int ch = 0; ch < 8; ++ch){
        if (ch < 7){
          int nt = (ch+1) >> 2, kb2 = ((ch+1) & 3)*8;
          const unsigned short* pn =
              wl2_l + ((size_t)((w*2+nt)*16 + mrow))*1024 + kb2*32 + kgrp*8;
          #pragma unroll
          for (int kc = 0; kc < 8; ++kc){
            short8 v = *(const short8*)(pn + kc*32);
            if (ch & 1) c0[kc] = v; else c1[kc] = v;
          }
        }
        int kb = (ch & 3)*8;
        short8 ah[8];
        #pragma unroll
        for (int kc = 0; kc < 8; ++kc)
          ah[kc] = *(const short8*)&hb[mrow][(kb+kc)*32 + kgrp*8];
        #pragma unroll
        for (int kc = 0; kc < 8; ++kc){
          short8 bb = (ch & 1) ? c1[kc] : c0[kc];
          if (ch >> 2)
            acc1 = __builtin_amdgcn_mfma_f32_16x16x32_bf16(ah[kc], bb, acc1, 0,0,0);
          else
            acc0 = __builtin_amdgcn_mfma_f32_16x16x32_bf16(ah[kc], bb, acc0, 0,0,0);
        }
      }
      #pragma unroll
      for (int u = 0; u < 2; ++u){
        f32x4 acc = u ? acc1 : acc0;
        int n_g = (w*2+u)*16 + mrow;
        float bias = bl2[l*256 + n_g];
        #pragma unroll
        for (int r = 0; r < 4; ++r){
          int br = kgrp*4 + r;
          zf[br][n_g] = acc[r] + bias + yf[br][n_g];
        }
      }
    }
    __syncthreads();

    // ===== LN3 (+ head @ l==11) + xh handoff + fin post =====
    {
      int row = tid >> 5, c8 = (lane & 31)*8;
      float tt[8];
      #pragma unroll
      for (int k = 0; k < 8; ++k) tt[k] = zf[row][c8+k];
      float sm = 0, sq = 0;
      #pragma unroll
      for (int k = 0; k < 8; ++k){ sm += tt[k]; sq += tt[k]*tt[k]; }
      sm += __shfl_xor(sm,1);  sq += __shfl_xor(sq,1);
      sm += __shfl_xor(sm,2);  sq += __shfl_xor(sq,2);
      sm += __shfl_xor(sm,4);  sq += __shfl_xor(sq,4);
      sm += __shfl_xor(sm,8);  sq += __shfl_xor(sq,8);
      sm += __shfl_xor(sm,16); sq += __shfl_xor(sq,16);
      float mean = sm*(1.f/256), var = sq*(1.f/256) - mean*mean;
      float rs = rsqrtf(var + EPS_);
      const float* g3p = g3 + l*256 + c8;
      const float* b3p = be3 + l*256 + c8;
      float xn[8];
      #pragma unroll
      for (int k = 0; k < 8; ++k)
        xn[k] = (tt[k]-mean)*rs*g3p[k] + b3p[k];

      float pr[4] = {0,0,0,0};
      const bool doHead = (l == 11);
      if (doHead){
        #pragma unroll
        for (int p = 0; p < 4; ++p){
          float a = 0.f;
          #pragma unroll
          for (int k = 0; k < 8; ++k) a += xn[k]*outW[p*256 + c8 + k];
          a += __shfl_xor(a,1); a += __shfl_xor(a,2);
          a += __shfl_xor(a,4); a += __shfl_xor(a,8);
          a += __shfl_xor(a,16);
          pr[p] = a;
        }
        if (t < 15){
          const float* pp = pos + (t+1)*256 + c8;
          #pragma unroll
          for (int k = 0; k < 8; ++k) xn[k] += pp[k];
        }
      }
      const bool last = (l == 11) && (t == 15);
      if (!last){
        unsigned long long* xp =
            xh + ((size_t)((l+1) & 1)*8 + grp)*2048 + (size_t)row*128 + (c8 >> 1);
        #pragma unroll
        for (int j = 0; j < 4; ++j)
          AS(xp + j, pack2f(xn[2*j], xn[2*j+1]));
      }
      __syncthreads();                    // drains xh stores (vmcnt 0)
      if (!last && tid == 0)
        AS(fin + l*8 + grp, t+1);
      if (doHead && ((lane & 31) == 0)){
        int gr = grp*16 + row;
        #pragma unroll
        for (int p = 0; p < 4; ++p){
          float v2 = pr[p] + outb[p];
          float sg = 1.f/(1.f + __expf(-v2));
          out[((size_t)gr*16 + t)*4 + p] = plow[p] + (phigh[p]-plow[p])*sg;
        }
      }
    }
  }
}

extern "C" void kernel_launch(void* const* d_in, const int* in_sizes, int n_in,
                              void* d_out, int out_size, void* d_ws, size_t ws_size,
                              hipStream_t stream) {
  const float* U_real = (const float*)d_in[0];
  const float* U_imag = (const float*)d_in[1];
  const float* tok_W  = (const float*)d_in[2];
  const float* tok_b  = (const float*)d_in[3];
  const float* pos    = (const float*)d_in[4];
  const float* saW    = (const float*)d_in[5];
  const float* sab    = (const float*)d_in[6];
  const float* saWo   = (const float*)d_in[7];
  const float* sabo   = (const float*)d_in[8];
  const float* caW    = (const float*)d_in[9];
  const float* cab    = (const float*)d_in[10];
  const float* caWo   = (const float*)d_in[11];
  const float* cabo   = (const float*)d_in[12];
  const float* l1W    = (const float*)d_in[13];
  const float* l1b    = (const float*)d_in[14];
  const float* l2W    = (const float*)d_in[15];
  const float* l2b    = (const float*)d_in[16];
  const float* g1     = (const float*)d_in[17];
  const float* be1    = (const float*)d_in[18];
  const float* g2     = (const float*)d_in[19];
  const float* be2    = (const float*)d_in[20];
  const float* g3     = (const float*)d_in[21];
  const float* be3    = (const float*)d_in[22];
  const float* outW   = (const float*)d_in[23];
  const float* outb   = (const float*)d_in[24];
  const float* plow   = (const float*)d_in[25];
  const float* phigh  = (const float*)d_in[26];

  char* ws = (char*)d_ws;
  unsigned short* wb        = (unsigned short*)(ws + OFF_WQKV);
  float* srcb               = (float*)(ws + OFF_SRC);
  unsigned short* ccb       = (unsigned short*)(ws + OFF_CC);
  unsigned short* kvc       = (unsigned short*)(ws + OFF_KV);
  unsigned long long* xhb   = (unsigned long long*)(ws + OFF_XH);
  int* flags                = (int*)(ws + OFF_FLG);

  (void)hipMemsetAsync(ws + OFF_FLG, 0, 512, stream);
  k_conv<<<dim3(4608), dim3(256), 0, stream>>>(saW, saWo, l1W, l2W, wb);
  k_src<<<dim3(128), dim3(256), 0, stream>>>(U_real, U_imag, tok_W, tok_b, pos,
                                             srcb, (float*)xhb);
  k_cc<<<dim3(1536), dim3(256), 0, stream>>>(caW, cab, caWo, cabo, srcb, ccb);
  k_main<<<dim3(128), dim3(512), 0, stream>>>(
      wb,
      (unsigned short*)(ws + OFF_WO),
      (unsigned short*)(ws + OFF_L1),
      (unsigned short*)(ws + OFF_L2),
      sab, sabo, l1b, l2b,
      g1, be1, g2, be2, g3, be3,
      ccb, pos, outW, outb, plow, phigh,
      kvc, xhb, flags, (float*)d_out);
}

// Round 12
// 5063.384 us; speedup vs baseline: 2.6376x; 2.6376x over previous
//
#include <hip/hip_runtime.h>
#include <hip/hip_bf16.h>

// ---------------------------------------------------------------------------
// CompositePulseTransformerDecoder — MI355X (gfx950), round 12
// SYSTOLIC PIPELINE, LAYER x SLICE x GROUP-SLOT:
// grid = 12 layers x 4 head-slices x GS group-slots (GS chosen at launch from
// ws_size: 4 / 2 / 1). Block (l,s,j) = r8's proven slice body, but handles
// only groups [j*(8/GS) .. +8/GS), cutting the serial critical path from
// 139 units (r8) to 16*(8/GS)+fill. XCD map keeps all GS blocks of one (l,s)
// on one XCD -> per-XCD distinct weights stay 2.3MB (r8's proven L2-resident
// regime; r11's 3.14MB/layer-block thrash avoided).
// Sync: fence-free relaxed agent atomics (r8): zA/zB partials per (l,j,s),
// fA/fB per (l,j), fin per (dest-l, src-slice, g), parity xh per (parity,g).
// Reuse safety: the 12-layer ring closes through every block, ordering all
// xh/zA/zB overwrites after their reads (same invariant r8 ran on).
// GS=1 reproduces r8 exactly (ws 46,010,368 B proven) — no-regression floor.
// ---------------------------------------------------------------------------

typedef __attribute__((ext_vector_type(8))) short short8;
typedef __attribute__((ext_vector_type(4))) float f32x4;

#define EPS_ 1e-5f

__device__ __forceinline__ unsigned short f2b(float x){
  union { float f; unsigned u; } c; c.f = x;
  unsigned r = (c.u + 0x7fffu + ((c.u >> 16) & 1u)) >> 16;
  return (unsigned short)r;
}
__device__ __forceinline__ float b2f(unsigned short u){
  union { unsigned u; float f; } c; c.u = ((unsigned)u) << 16;
  return c.f;
}
__device__ __forceinline__ unsigned long long pack4b(const f32x4 a){
  return (unsigned long long)f2b(a[0]) |
         ((unsigned long long)f2b(a[1]) << 16) |
         ((unsigned long long)f2b(a[2]) << 32) |
         ((unsigned long long)f2b(a[3]) << 48);
}
__device__ __forceinline__ unsigned long long pack2f(float a, float b){
  union { float f; unsigned u; } x, y; x.f = a; y.f = b;
  return (unsigned long long)x.u | ((unsigned long long)y.u << 32);
}
__device__ __forceinline__ float lo_f(unsigned long long v){
  union { unsigned u; float f; } c; c.u = (unsigned)v; return c.f;
}
__device__ __forceinline__ float hi_f(unsigned long long v){
  union { unsigned u; float f; } c; c.u = (unsigned)(v >> 32); return c.f;
}

#define AL(p)    __hip_atomic_load((p),  __ATOMIC_RELAXED, __HIP_MEMORY_SCOPE_AGENT)
#define AS(p,v)  __hip_atomic_store((p), (v), __ATOMIC_RELAXED, __HIP_MEMORY_SCOPE_AGENT)

// fixed ws layout (bytes); zA/zB/flags offsets depend on GS (computed at launch)
#define OFF_WQKV 0ull            // 12*768*256  bf16 = 4,718,592
#define OFF_WO   4718592ull      // 12*256*256  bf16 = 1,572,864
#define OFF_L1   6291456ull      // 12*1024*256 bf16 = 6,291,456
#define OFF_L2   12582912ull     // 12*256*1024 bf16 = 6,291,456
#define OFF_SRC  18874368ull     // 128*256 f32 = 131,072
#define OFF_CC   19005440ull     // 12*128*256 bf16 = 786,432
#define OFF_KV   19791872ull     // [12][4][8][16][16][128] bf16 = 25,165,824
#define OFF_XH   44957696ull     // [2][8][16][128] u64 = 262,144
#define OFF_DYN  45219840ull     // zA | zB | flags (GS-dependent)

// ---------------- weight f32 -> bf16 conversion --------------------------
__global__ void k_conv(const float* __restrict__ wqkv, const float* __restrict__ wo,
                       const float* __restrict__ l1, const float* __restrict__ l2,
                       unsigned short* __restrict__ dst){
  const long long n0 = 12LL*768*256;
  const long long n1 = n0 + 12LL*256*256;
  const long long n2 = n1 + 12LL*1024*256;
  const long long n3 = n2 + 12LL*256*1024;
  for (long long idx = (long long)blockIdx.x*256 + threadIdx.x; idx < n3;
       idx += (long long)gridDim.x*256){
    float v;
    if (idx < n0) v = wqkv[idx];
    else if (idx < n1) v = wo[idx - n0];
    else if (idx < n2) v = l1[idx - n1];
    else v = l2[idx - n2];
    dst[idx] = f2b(v);
  }
}

// -------- src = vec @ tok_W.T + tok_b ;  prime xh parity-0 ---------------
__global__ void k_src(const float* __restrict__ U_real, const float* __restrict__ U_imag,
                      const float* __restrict__ tok_W, const float* __restrict__ tok_b,
                      const float* __restrict__ pos,
                      float* __restrict__ src, float* __restrict__ xh0){
  int b = blockIdx.x, n = threadIdx.x;
  const float* w = tok_W + n*128;
  const float* ur = U_real + b*64;
  const float* ui = U_imag + b*64;
  float acc = tok_b[n];
  #pragma unroll 8
  for (int k = 0; k < 64; ++k) acc += w[k]*ur[k];
  #pragma unroll 8
  for (int k = 0; k < 64; ++k) acc += w[64+k]*ui[k];
  src[b*256+n] = acc;               // raw src (for k_cc)
  xh0[b*256+n] = acc + pos[n];      // token-0 input = src + pos[0]
}

// ------- cross-attn constant: cc[l][b] = Wo_ca @ (Wv_ca@src_b + bv) + bo --
__global__ void k_cc(const float* __restrict__ caW, const float* __restrict__ cab,
                     const float* __restrict__ caWo, const float* __restrict__ cabo,
                     const float* __restrict__ src, unsigned short* __restrict__ cc){
  int l = blockIdx.x >> 7, b = blockIdx.x & 127, t = threadIdx.x;
  __shared__ float v[256];
  const float* s = src + b*256;
  {
    const float* w = caW + ((long long)l*768 + 512 + t)*256;
    float a = cab[l*768 + 512 + t];
    #pragma unroll 8
    for (int k = 0; k < 256; ++k) a += w[k]*s[k];
    v[t] = a;
  }
  __syncthreads();
  {
    const float* w = caWo + ((long long)l*256 + t)*256;
    float a = cabo[l*256 + t];
    #pragma unroll 8
    for (int k = 0; k < 256; ++k) a += w[k]*v[k];
    cc[((long long)l*128 + b)*256 + t] = f2b(a);
  }
}

// ---------------- main systolic kernel -----------------------------------
// intra-quad sync among 4 slice-blocks of (l,j)
#define PUBW(FARR) do{                                                       \
  __syncthreads();                                                           \
  if (tid == 0) AS(FARR + quad*4 + h, seq);                                  \
  if (tid < 3){                                                              \
    int ho = tid + (tid >= h ? 1 : 0);                                       \
    const int* fp = FARR + quad*4 + ho;                                      \
    while (AL(fp) < seq) __builtin_amdgcn_s_sleep(1);                        \
  }                                                                          \
  __syncthreads();                                                           \
}while(0)

__global__ __launch_bounds__(512, 1) void k_main(
  const unsigned short* __restrict__ wqkv,   // [12][768][256] bf16
  const unsigned short* __restrict__ wo,     // [12][256][256]
  const unsigned short* __restrict__ wl1,    // [12][1024][256]
  const unsigned short* __restrict__ wl2,    // [12][256][1024]
  const float* __restrict__ bqkv, const float* __restrict__ bo_,
  const float* __restrict__ bl1,  const float* __restrict__ bl2,
  const float* __restrict__ g1, const float* __restrict__ be1,
  const float* __restrict__ g2, const float* __restrict__ be2,
  const float* __restrict__ g3, const float* __restrict__ be3,
  const unsigned short* __restrict__ cc,     // [12][128][256] bf16
  const float* __restrict__ pos,             // [17][256]
  const float* __restrict__ outW,            // [4][256]
  const float* __restrict__ outb,
  const float* __restrict__ plow, const float* __restrict__ phigh,
  unsigned short* __restrict__ kvc,          // [12][4][8][16][16][128] bf16
  unsigned long long* __restrict__ xh,       // [2][8][16][128] u64
  unsigned long long* __restrict__ zA,       // [12*GS][4][256][4] u64
  unsigned long long* __restrict__ zB,       // [12*GS][4][256][4] u64
  int* __restrict__ flags,                   // fin[12][4][8] | fA[12*GS][4] | fB
  int GS, int lgGS,                          // group slots (1/2/4), log2
  float* __restrict__ out)                   // [128][16][4]
{
  __shared__ float xf[16][260];
  __shared__ float zf[16][260];
  __shared__ float yf[16][260];
  __shared__ unsigned short xb[16][264];
  __shared__ unsigned short hs[16][264];
  __shared__ unsigned short qs[16][72];
  __shared__ unsigned short os[16][72];

  const int tid  = threadIdx.x;
  const int w    = tid >> 6, lane = tid & 63;
  const int mrow = lane & 15, kgrp = lane >> 4;

  // bid -> (l, s=h, j): all GS blocks of one (l,s) share XCD (bid%8)
  const int xcd      = blockIdx.x & 7;
  const int q        = blockIdx.x >> 3;
  const int j        = q & (GS - 1);
  const int pairSlot = q >> lgGS;            // 0..5
  const int pair     = xcd + 8*pairSlot;     // l*4+s
  const int l        = pair >> 2;
  const int h        = pair & 3;
  const int quad     = l*GS + j;             // fA/fB/zA/zB row
  const int GPB      = 8 >> lgGS;            // groups per block
  const int g0       = j*GPB;

  int* fin = flags;                 // [12][4][8]
  int* fA  = flags + 384;           // [12*GS][4]
  int* fB  = fA + 48*GS;            // [12*GS][4]

  for (int t = 0; t < 16; ++t){
    for (int gg = 0; gg < GPB; ++gg){
      const int g   = g0 + gg;
      const int seq = t*GPB + gg + 1;

      // ===== wait upstream (4 slices of prev layer), read xh =====
      {
        int need = (l == 0) ? t : (t+1);
        if (need > 0 && tid < 4){
          const int* fp = fin + (l*4 + tid)*8 + g;
          while (AL(fp) < need) __builtin_amdgcn_s_sleep(1);
        }
        __syncthreads();
        int row = tid >> 5, c8 = (tid & 31)*8;
        const unsigned long long* xp =
            xh + ((size_t)(l & 1)*8 + g)*2048 + (size_t)row*128 + (c8 >> 1);
        #pragma unroll
        for (int jj = 0; jj < 4; ++jj){
          unsigned long long v = AL(xp + jj);
          float f0 = lo_f(v), f1 = hi_f(v);
          xf[row][c8+2*jj]   = f0;  xf[row][c8+2*jj+1] = f1;
          xb[row][c8+2*jj]   = f2b(f0);
          xb[row][c8+2*jj+1] = f2b(f1);
        }
      }
      __syncthreads();

      // ===== QKV (head h): 12 n-tiles over 8 waves =====
      {
        short8 a[8];
        #pragma unroll
        for (int kc = 0; kc < 8; ++kc)
          a[kc] = *(const short8*)&xb[mrow][kc*32 + kgrp*8];
        const unsigned short* wl = wqkv + (size_t)l*196608;
        for (int t2 = w; t2 < 12; t2 += 8){
          int p = t2 >> 2, q4 = t2 & 3;
          int n_l = q4*16 + mrow;
          const unsigned short* wp = wl + (size_t)(p*256 + h*64 + n_l)*256 + kgrp*8;
          f32x4 acc = {0,0,0,0};
          #pragma unroll
          for (int kc = 0; kc < 8; ++kc){
            short8 b0 = *(const short8*)(wp + kc*32);
            acc = __builtin_amdgcn_mfma_f32_16x16x32_bf16(a[kc], b0, acc, 0,0,0);
          }
          float bias = bqkv[l*768 + p*256 + h*64 + n_l];
          #pragma unroll
          for (int r = 0; r < 4; ++r){
            int br = kgrp*4 + r;
            float v = acc[r] + bias;
            if (p == 0){
              qs[br][n_l] = f2b(v);
            } else {
              size_t kb = (((((size_t)l*4 + h)*8 + g)*16 + br)*16 + t)*128
                          + (p == 2 ? 64 : 0) + n_l;
              kvc[kb] = f2b(v);
            }
          }
        }
      }
      __syncthreads();

      // ===== attention (head h, block-local KV) =====
      {
        int row = w*2 + (lane >> 5);
        int lid = lane & 31;
        float q0v = b2f(qs[row][lid*2]), q1v = b2f(qs[row][lid*2+1]);
        const unsigned short* base =
            kvc + (((((size_t)l*4 + h)*8 + g)*16 + row)*16)*128 + lid*2;
        float sv[16];
        #pragma unroll
        for (int jj = 0; jj < 16; ++jj){
          if (jj <= t){
            const unsigned short* kp = base + jj*128;
            float p = q0v*b2f(kp[0]) + q1v*b2f(kp[1]);
            p += __shfl_xor(p, 1);
            p += __shfl_xor(p, 2);
            p += __shfl_xor(p, 4);
            p += __shfl_xor(p, 8);
            p += __shfl_xor(p, 16);
            sv[jj] = p * 0.125f;
          } else sv[jj] = -1e30f;
        }
        float mx = sv[0];
        #pragma unroll
        for (int jj = 1; jj < 16; ++jj) mx = fmaxf(mx, sv[jj]);
        float den = 0.f, e[16];
        #pragma unroll
        for (int jj = 0; jj < 16; ++jj){ e[jj] = __expf(sv[jj]-mx); den += e[jj]; }
        float rd = 1.f/den;
        float o0 = 0.f, o1 = 0.f;
        #pragma unroll
        for (int jj = 0; jj < 16; ++jj){
          if (jj <= t){
            const unsigned short* vp = base + jj*128 + 64;
            o0 += e[jj]*b2f(vp[0]);
            o1 += e[jj]*b2f(vp[1]);
          }
        }
        os[row][lid*2]   = f2b(o0*rd);
        os[row][lid*2+1] = f2b(o1*rd);
      }
      __syncthreads();

      // ===== Wo K-split partial -> zA =====
      {
        short8 a2[2];
        #pragma unroll
        for (int kc = 0; kc < 2; ++kc)
          a2[kc] = *(const short8*)&os[mrow][kc*32 + kgrp*8];
        #pragma unroll
        for (int u2 = 0; u2 < 2; ++u2){
          int n_g = (w*2+u2)*16 + mrow;
          const unsigned short* wp = wo + (size_t)l*65536 + (size_t)n_g*256 + h*64 + kgrp*8;
          f32x4 acc = {0,0,0,0};
          #pragma unroll
          for (int kc = 0; kc < 2; ++kc){
            short8 b0 = *(const short8*)(wp + kc*32);
            acc = __builtin_amdgcn_mfma_f32_16x16x32_bf16(a2[kc], b0, acc, 0,0,0);
          }
          AS(zA + ((size_t)(quad*4 + h)*256 + n_g)*4 + kgrp, pack4b(acc));
        }
      }
      PUBW(fA);

      // ===== sum zA -> zf (+bias +residual) =====
      {
        int col = tid & 255, rq2 = tid >> 8;
        float a8[8] = {0,0,0,0,0,0,0,0};
        #pragma unroll
        for (int s4 = 0; s4 < 4; ++s4){
          const unsigned long long* bp = zA + ((size_t)(quad*4 + s4)*256 + col)*4 + rq2*2;
          #pragma unroll
          for (int qq = 0; qq < 2; ++qq){
            unsigned long long v = AL(bp + qq);
            a8[qq*4+0] += b2f((unsigned short)v);
            a8[qq*4+1] += b2f((unsigned short)(v >> 16));
            a8[qq*4+2] += b2f((unsigned short)(v >> 32));
            a8[qq*4+3] += b2f((unsigned short)(v >> 48));
          }
        }
        float bias = bo_[l*256 + col];
        #pragma unroll
        for (int r = 0; r < 8; ++r){
          int row = rq2*8 + r;
          zf[row][col] = a8[r] + bias + xf[row][col];
        }
      }
      __syncthreads();

      // ===== LN1 + cc + LN2 -> yf, xb =====
      {
        int row = tid >> 5, c8 = (tid & 31)*8;
        float tt[8];
        #pragma unroll
        for (int k = 0; k < 8; ++k) tt[k] = zf[row][c8+k];
        float sm = 0, sq = 0;
        #pragma unroll
        for (int k = 0; k < 8; ++k){ sm += tt[k]; sq += tt[k]*tt[k]; }
        sm += __shfl_xor(sm,1);  sq += __shfl_xor(sq,1);
        sm += __shfl_xor(sm,2);  sq += __shfl_xor(sq,2);
        sm += __shfl_xor(sm,4);  sq += __shfl_xor(sq,4);
        sm += __shfl_xor(sm,8);  sq += __shfl_xor(sq,8);
        sm += __shfl_xor(sm,16); sq += __shfl_xor(sq,16);
        float mean = sm*(1.f/256), var = sq*(1.f/256) - mean*mean;
        float rs = rsqrtf(var + EPS_);
        const float* g1p = g1 + l*256 + c8;
        const float* b1p = be1 + l*256 + c8;
        const unsigned short* ccp = cc + ((size_t)l*128 + g*16 + row)*256 + c8;
        #pragma unroll
        for (int k = 0; k < 8; ++k)
          tt[k] = (tt[k]-mean)*rs*g1p[k] + b1p[k] + b2f(ccp[k]);
        sm = 0; sq = 0;
        #pragma unroll
        for (int k = 0; k < 8; ++k){ sm += tt[k]; sq += tt[k]*tt[k]; }
        sm += __shfl_xor(sm,1);  sq += __shfl_xor(sq,1);
        sm += __shfl_xor(sm,2);  sq += __shfl_xor(sq,2);
        sm += __shfl_xor(sm,4);  sq += __shfl_xor(sq,4);
        sm += __shfl_xor(sm,8);  sq += __shfl_xor(sq,8);
        sm += __shfl_xor(sm,16); sq += __shfl_xor(sq,16);
        mean = sm*(1.f/256); var = sq*(1.f/256) - mean*mean;
        rs = rsqrtf(var + EPS_);
        const float* g2p = g2 + l*256 + c8;
        const float* b2p = be2 + l*256 + c8;
        #pragma unroll
        for (int k = 0; k < 8; ++k){
          float y = (tt[k]-mean)*rs*g2p[k] + b2p[k];
          yf[row][c8+k] = y;
          xb[row][c8+k] = f2b(y);
        }
      }
      __syncthreads();

      // ===== lin1 N-slice (h*256..+256) + relu -> hs =====
      {
        short8 a[8];
        #pragma unroll
        for (int kc = 0; kc < 8; ++kc)
          a[kc] = *(const short8*)&xb[mrow][kc*32 + kgrp*8];
        const unsigned short* wl = wl1 + (size_t)l*262144;
        #pragma unroll
        for (int u2 = 0; u2 < 2; ++u2){
          int n_sl = (w*2+u2)*16 + mrow;
          const unsigned short* wp = wl + (size_t)(h*256 + n_sl)*256 + kgrp*8;
          f32x4 acc = {0,0,0,0};
          #pragma unroll
          for (int kc = 0; kc < 8; ++kc){
            short8 b0 = *(const short8*)(wp + kc*32);
            acc = __builtin_amdgcn_mfma_f32_16x16x32_bf16(a[kc], b0, acc, 0,0,0);
          }
          float bias = bl1[l*1024 + h*256 + n_sl];
          #pragma unroll
          for (int r = 0; r < 4; ++r){
            float hv = acc[r] + bias;
            hs[kgrp*4 + r][n_sl] = f2b(hv > 0.f ? hv : 0.f);
          }
        }
      }
      __syncthreads();

      // ===== lin2 K-split partial -> zB =====
      {
        short8 ah[8];
        #pragma unroll
        for (int kc = 0; kc < 8; ++kc)
          ah[kc] = *(const short8*)&hs[mrow][kc*32 + kgrp*8];
        #pragma unroll
        for (int u2 = 0; u2 < 2; ++u2){
          int n_g = (w*2+u2)*16 + mrow;
          const unsigned short* wp = wl2 + (size_t)l*262144 + (size_t)n_g*1024 + h*256 + kgrp*8;
          f32x4 acc = {0,0,0,0};
          #pragma unroll
          for (int kc = 0; kc < 8; ++kc){
            short8 b0 = *(const short8*)(wp + kc*32);
            acc = __builtin_amdgcn_mfma_f32_16x16x32_bf16(ah[kc], b0, acc, 0,0,0);
          }
          AS(zB + ((size_t)(quad*4 + h)*256 + n_g)*4 + kgrp, pack4b(acc));
        }
      }
      PUBW(fB);

      // ===== sum zB -> zf (+bias +yf residual) =====
      {
        int col = tid & 255, rq2 = tid >> 8;
        float a8[8] = {0,0,0,0,0,0,0,0};
        #pragma unroll
        for (int s4 = 0; s4 < 4; ++s4){
          const unsigned long long* bp = zB + ((size_t)(quad*4 + s4)*256 + col)*4 + rq2*2;
          #pragma unroll
          for (int qq = 0; qq < 2; ++qq){
            unsigned long long v = AL(bp + qq);
            a8[qq*4+0] += b2f((unsigned short)v);
            a8[qq*4+1] += b2f((unsigned short)(v >> 16));
            a8[qq*4+2] += b2f((unsigned short)(v >> 32));
            a8[qq*4+3] += b2f((unsigned short)(v >> 48));
          }
        }
        float bias = bl2[l*256 + col];
        #pragma unroll
        for (int r = 0; r < 8; ++r){
          int row = rq2*8 + r;
          zf[row][col] = a8[r] + bias + yf[row][col];
        }
      }
      __syncthreads();

      // ===== LN3 + handoff + fin post (+ head @ l==11) =====
      {
        int row = tid >> 5, c8 = (tid & 31)*8;
        float tt[8];
        #pragma unroll
        for (int k = 0; k < 8; ++k) tt[k] = zf[row][c8+k];
        float sm = 0, sq = 0;
        #pragma unroll
        for (int k = 0; k < 8; ++k){ sm += tt[k]; sq += tt[k]*tt[k]; }
        sm += __shfl_xor(sm,1);  sq += __shfl_xor(sq,1);
        sm += __shfl_xor(sm,2);  sq += __shfl_xor(sq,2);
        sm += __shfl_xor(sm,4);  sq += __shfl_xor(sq,4);
        sm += __shfl_xor(sm,8);  sq += __shfl_xor(sq,8);
        sm += __shfl_xor(sm,16); sq += __shfl_xor(sq,16);
        float mean = sm*(1.f/256), var = sq*(1.f/256) - mean*mean;
        float rs = rsqrtf(var + EPS_);
        const float* g3p = g3 + l*256 + c8;
        const float* b3p = be3 + l*256 + c8;
        float xn[8];
        #pragma unroll
        for (int k = 0; k < 8; ++k)
          xn[k] = (tt[k]-mean)*rs*g3p[k] + b3p[k];

        float pr[4] = {0,0,0,0};
        const bool doHead = (l == 11) && (h == 0);
        if (doHead){
          #pragma unroll
          for (int p = 0; p < 4; ++p){
            float a = 0.f;
            #pragma unroll
            for (int k = 0; k < 8; ++k) a += xn[k]*outW[p*256 + c8 + k];
            a += __shfl_xor(a,1); a += __shfl_xor(a,2);
            a += __shfl_xor(a,4); a += __shfl_xor(a,8);
            a += __shfl_xor(a,16);
            pr[p] = a;
          }
        }
        if (l == 11 && t < 15){
          const float* pp = pos + (t+1)*256 + c8;
          #pragma unroll
          for (int k = 0; k < 8; ++k) xn[k] += pp[k];
        }
        const bool last = (l == 11) && (t == 15);
        if (!last && ((c8 >> 6) == h)){
          unsigned long long* xp =
              xh + ((size_t)((l+1) & 1)*8 + g)*2048 + (size_t)row*128 + (c8 >> 1);
          #pragma unroll
          for (int jj = 0; jj < 4; ++jj)
            AS(xp + jj, pack2f(xn[2*jj], xn[2*jj+1]));
        }
        __syncthreads();                    // drains xh stores
        if (!last && tid == 0)
          AS(fin + (((l+1) % 12)*4 + h)*8 + g, t+1);
        if (doHead && ((tid & 31) == 0)){
          int gr = g*16 + row;
          #pragma unroll
          for (int p = 0; p < 4; ++p){
            float v2 = pr[p] + outb[p];
            float sg = 1.f/(1.f + __expf(-v2));
            out[((size_t)gr*16 + t)*4 + p] = plow[p] + (phigh[p]-plow[p])*sg;
          }
        }
      }
    }
  }
}

extern "C" void kernel_launch(void* const* d_in, const int* in_sizes, int n_in,
                              void* d_out, int out_size, void* d_ws, size_t ws_size,
                              hipStream_t stream) {
  const float* U_real = (const float*)d_in[0];
  const float* U_imag = (const float*)d_in[1];
  const float* tok_W  = (const float*)d_in[2];
  const float* tok_b  = (const float*)d_in[3];
  const float* pos    = (const float*)d_in[4];
  const float* saW    = (const float*)d_in[5];
  const float* sab    = (const float*)d_in[6];
  const float* saWo   = (const float*)d_in[7];
  const float* sabo   = (const float*)d_in[8];
  const float* caW    = (const float*)d_in[9];
  const float* cab    = (const float*)d_in[10];
  const float* caWo   = (const float*)d_in[11];
  const float* cabo   = (const float*)d_in[12];
  const float* l1W    = (const float*)d_in[13];
  const float* l1b    = (const float*)d_in[14];
  const float* l2W    = (const float*)d_in[15];
  const float* l2b    = (const float*)d_in[16];
  const float* g1     = (const float*)d_in[17];
  const float* be1    = (const float*)d_in[18];
  const float* g2     = (const float*)d_in[19];
  const float* be2    = (const float*)d_in[20];
  const float* g3     = (const float*)d_in[21];
  const float* be3    = (const float*)d_in[22];
  const float* outW   = (const float*)d_in[23];
  const float* outb   = (const float*)d_in[24];
  const float* plow   = (const float*)d_in[25];
  const float* phigh  = (const float*)d_in[26];

  // choose GS (group slots) from ws_size; GS=1 == r8 exactly (proven size)
  int GS = 1, lgGS = 0;
  {
    auto need = [](int gs) -> size_t {
      size_t za = (size_t)12 * gs * 4 * 256 * 4 * 8;   // u64
      return (size_t)OFF_DYN + 2*za + 4096;
    };
    if (ws_size >= need(4))      { GS = 4; lgGS = 2; }
    else if (ws_size >= need(2)) { GS = 2; lgGS = 1; }
  }
  size_t zaBytes = (size_t)12 * GS * 4 * 256 * 4 * 8;

  char* ws = (char*)d_ws;
  unsigned short* wb        = (unsigned short*)(ws + OFF_WQKV);
  float* srcb               = (float*)(ws + OFF_SRC);
  unsigned short* ccb       = (unsigned short*)(ws + OFF_CC);
  unsigned short* kvc       = (unsigned short*)(ws + OFF_KV);
  unsigned long long* xhb   = (unsigned long long*)(ws + OFF_XH);
  unsigned long long* zAb   = (unsigned long long*)(ws + OFF_DYN);
  unsigned long long* zBb   = (unsigned long long*)(ws + OFF_DYN + zaBytes);
  int* flags                = (int*)(ws + OFF_DYN + 2*zaBytes);

  (void)hipMemsetAsync(ws + OFF_DYN + 2*zaBytes, 0, 4096, stream);
  k_conv<<<dim3(4608), dim3(256), 0, stream>>>(saW, saWo, l1W, l2W, wb);
  k_src<<<dim3(128), dim3(256), 0, stream>>>(U_real, U_imag, tok_W, tok_b, pos,
                                             srcb, (float*)xhb);
  k_cc<<<dim3(1536), dim3(256), 0, stream>>>(caW, cab, caWo, cabo, srcb, ccb);
  k_main<<<dim3(48*GS), dim3(512), 0, stream>>>(
      wb,
      (unsigned short*)(ws + OFF_WO),
      (unsigned short*)(ws + OFF_L1),
      (unsigned short*)(ws + OFF_L2),
      sab, sabo, l1b, l2b,
      g1, be1, g2, be2, g3, be3,
      ccb, pos, outW, outb, plow, phigh,
      kvc, xhb, zAb, zBb, flags, GS, lgGS, (float*)d_out);
}

// Round 13
// 4524.701 us; speedup vs baseline: 2.9516x; 1.1191x over previous
//
#include <hip/hip_runtime.h>
#include <hip/hip_bf16.h>

// ---------------------------------------------------------------------------
// CompositePulseTransformerDecoder — MI355X (gfx950), round 13
// r8 SYSTOLIC PIPELINE (12 layers x 4 head-slices, 48 blocks x 512 thr) with
// GLOBAL_LOAD_LDS DEEP-ASYNC WEIGHT STAGING:
//  - k_conv packs weights fragment-major: [l][h][tile16][kc][lane][8xbf16]
//    so each lane's MFMA B-fragment is the linear lane*16B LDS pattern.
//  - each wave stages its tiles into a wave-private 8KB LDS buffer via
//    __builtin_amdgcn_global_load_lds(16B) — no dest VGPRs, 8KB in flight
//    per wave (r8's direct loads sustained only ~1KB) -> ~8x stream rate.
//  - no extra barriers: wave-private buffers, vmcnt(0) + sched_barrier fences.
// Protocol/numerics identical to r8 (fence-free relaxed atomics; zA/zB/fin).
// ---------------------------------------------------------------------------

typedef __attribute__((ext_vector_type(8))) short short8;
typedef __attribute__((ext_vector_type(4))) float f32x4;

#define EPS_ 1e-5f

__device__ __forceinline__ unsigned short f2b(float x){
  union { float f; unsigned u; } c; c.f = x;
  unsigned r = (c.u + 0x7fffu + ((c.u >> 16) & 1u)) >> 16;
  return (unsigned short)r;
}
__device__ __forceinline__ float b2f(unsigned short u){
  union { unsigned u; float f; } c; c.u = ((unsigned)u) << 16;
  return c.f;
}
__device__ __forceinline__ unsigned long long pack4b(const f32x4 a){
  return (unsigned long long)f2b(a[0]) |
         ((unsigned long long)f2b(a[1]) << 16) |
         ((unsigned long long)f2b(a[2]) << 32) |
         ((unsigned long long)f2b(a[3]) << 48);
}
__device__ __forceinline__ unsigned long long pack2f(float a, float b){
  union { float f; unsigned u; } x, y; x.f = a; y.f = b;
  return (unsigned long long)x.u | ((unsigned long long)y.u << 32);
}
__device__ __forceinline__ float lo_f(unsigned long long v){
  union { unsigned u; float f; } c; c.u = (unsigned)v; return c.f;
}
__device__ __forceinline__ float hi_f(unsigned long long v){
  union { unsigned u; float f; } c; c.u = (unsigned)(v >> 32); return c.f;
}

#define AL(p)    __hip_atomic_load((p),  __ATOMIC_RELAXED, __HIP_MEMORY_SCOPE_AGENT)
#define AS(p,v)  __hip_atomic_store((p), (v), __ATOMIC_RELAXED, __HIP_MEMORY_SCOPE_AGENT)

// async global->LDS, 16B per lane; LDS dest = uniform base + lane*16
__device__ __forceinline__ void gload16(const unsigned short* g, unsigned short* l){
  __builtin_amdgcn_global_load_lds(
      (const __attribute__((address_space(1))) unsigned int*)g,
      (__attribute__((address_space(3))) unsigned int*)l, 16, 0, 0);
}
#define WAIT_STG() do{ asm volatile("s_waitcnt vmcnt(0)" ::: "memory");      \
                       __builtin_amdgcn_sched_barrier(0); }while(0)
#define PIN_ORDER() __builtin_amdgcn_sched_barrier(0)

// ws layout (bytes) — identical totals to r8 (46,010,368 proven)
#define OFF_WQKV 0ull            // packed QKV  [12][4][12][4096] bf16 = 4,718,592
#define OFF_WO   4718592ull      // packed Wo   [12][4][16][1024] bf16 = 1,572,864
#define OFF_L1   6291456ull      // packed lin1 [12][4][16][4096] bf16 = 6,291,456
#define OFF_L2   12582912ull     // packed lin2 [12][4][16][4096] bf16 = 6,291,456
#define OFF_SRC  18874368ull     // 128*256 f32 = 131,072
#define OFF_CC   19005440ull     // 12*128*256 bf16 = 786,432
#define OFF_KV   19791872ull     // [12][4][8][16][16][128] bf16 = 25,165,824
#define OFF_XH   44957696ull     // [2][8][16][128] u64 = 262,144
#define OFF_ZA   45219840ull     // [12][4][256][4] u64 = 393,216
#define OFF_ZB   45613056ull     // [12][4][256][4] u64 = 393,216
#define OFF_FLG  46006272ull     // fin[12][4][8] @0, fA[12][4] @384, fB @432

// ------- weight f32 -> packed bf16 fragments -----------------------------
// fragment layout per 16-row tile: [kc][lane][e]; value =
//   W[n0 + (lane&15)][k0 + (lane>>4)*8 + kc*32 + e]
__global__ void k_conv(const float* __restrict__ wqkv, const float* __restrict__ wo,
                       const float* __restrict__ l1, const float* __restrict__ l2,
                       unsigned short* __restrict__ dst){
  const long long nQ = 2359296, nW = 786432, nL1 = 3145728;
  const long long tot = 9437184;
  for (long long idx = (long long)blockIdx.x*256 + threadIdx.x; idx < tot;
       idx += (long long)gridDim.x*256){
    float v;
    long long i = idx;
    if (i < nQ){
      int l = (int)(i/196608); int r = (int)(i%196608);
      int h = r/49152; r %= 49152;
      int tile = r/4096; r %= 4096;
      int kc = r>>9; int lane = (r>>3)&63; int e = r&7;
      int p = tile>>2, q4 = tile&3;
      int n = p*256 + h*64 + q4*16 + (lane&15);
      int k = (lane>>4)*8 + kc*32 + e;
      v = wqkv[((long long)l*768 + n)*256 + k];
    } else if (i < nQ+nW){
      i -= nQ;
      int l = (int)(i/65536); int r = (int)(i%65536);
      int h = r/16384; r %= 16384;
      int tile = r/1024; r %= 1024;
      int kc = r>>9; int lane = (r>>3)&63; int e = r&7;
      int n = tile*16 + (lane&15);
      int k = h*64 + (lane>>4)*8 + kc*32 + e;
      v = wo[((long long)l*256 + n)*256 + k];
    } else if (i < nQ+nW+nL1){
      i -= nQ+nW;
      int l = (int)(i/262144); int r = (int)(i%262144);
      int h = r/65536; r %= 65536;
      int tile = r/4096; r %= 4096;
      int kc = r>>9; int lane = (r>>3)&63; int e = r&7;
      int n = h*256 + tile*16 + (lane&15);
      int k = (lane>>4)*8 + kc*32 + e;
      v = l1[((long long)l*1024 + n)*256 + k];
    } else {
      i -= nQ+nW+nL1;
      int l = (int)(i/262144); int r = (int)(i%262144);
      int h = r/65536; r %= 65536;
      int tile = r/4096; r %= 4096;
      int kc = r>>9; int lane = (r>>3)&63; int e = r&7;
      int n = tile*16 + (lane&15);
      int k = h*256 + (lane>>4)*8 + kc*32 + e;
      v = l2[((long long)l*256 + n)*1024 + k];
    }
    dst[idx] = f2b(v);
  }
}

// -------- src = vec @ tok_W.T + tok_b ;  prime xh parity-0 ---------------
__global__ void k_src(const float* __restrict__ U_real, const float* __restrict__ U_imag,
                      const float* __restrict__ tok_W, const float* __restrict__ tok_b,
                      const float* __restrict__ pos,
                      float* __restrict__ src, float* __restrict__ xh0){
  int b = blockIdx.x, n = threadIdx.x;
  const float* w = tok_W + n*128;
  const float* ur = U_real + b*64;
  const float* ui = U_imag + b*64;
  float acc = tok_b[n];
  #pragma unroll 8
  for (int k = 0; k < 64; ++k) acc += w[k]*ur[k];
  #pragma unroll 8
  for (int k = 0; k < 64; ++k) acc += w[64+k]*ui[k];
  src[b*256+n] = acc;
  xh0[b*256+n] = acc + pos[n];
}

// ------- cross-attn constant ---------------------------------------------
__global__ void k_cc(const float* __restrict__ caW, const float* __restrict__ cab,
                     const float* __restrict__ caWo, const float* __restrict__ cabo,
                     const float* __restrict__ src, unsigned short* __restrict__ cc){
  int l = blockIdx.x >> 7, b = blockIdx.x & 127, t = threadIdx.x;
  __shared__ float v[256];
  const float* s = src + b*256;
  {
    const float* w = caW + ((long long)l*768 + 512 + t)*256;
    float a = cab[l*768 + 512 + t];
    #pragma unroll 8
    for (int k = 0; k < 256; ++k) a += w[k]*s[k];
    v[t] = a;
  }
  __syncthreads();
  {
    const float* w = caWo + ((long long)l*256 + t)*256;
    float a = cabo[l*256 + t];
    #pragma unroll 8
    for (int k = 0; k < 256; ++k) a += w[k]*v[k];
    cc[((long long)l*128 + b)*256 + t] = f2b(a);
  }
}

// ---------------- main systolic kernel -----------------------------------
#define PUBW(FARR) do{                                                       \
  __syncthreads();                                                           \
  if (tid == 0) AS(FARR + l*4 + h, seq);                                     \
  if (tid < 3){                                                              \
    int ho = tid + (tid >= h ? 1 : 0);                                       \
    const int* fp = FARR + l*4 + ho;                                         \
    while (AL(fp) < seq) __builtin_amdgcn_s_sleep(1);                        \
  }                                                                          \
  __syncthreads();                                                           \
}while(0)

__global__ __launch_bounds__(512, 1) void k_main(
  const unsigned short* __restrict__ wqkv,   // packed
  const unsigned short* __restrict__ wo,     // packed
  const unsigned short* __restrict__ wl1,    // packed
  const unsigned short* __restrict__ wl2,    // packed
  const float* __restrict__ bqkv, const float* __restrict__ bo_,
  const float* __restrict__ bl1,  const float* __restrict__ bl2,
  const float* __restrict__ g1, const float* __restrict__ be1,
  const float* __restrict__ g2, const float* __restrict__ be2,
  const float* __restrict__ g3, const float* __restrict__ be3,
  const unsigned short* __restrict__ cc,
  const float* __restrict__ pos,
  const float* __restrict__ outW,
  const float* __restrict__ outb,
  const float* __restrict__ plow, const float* __restrict__ phigh,
  unsigned short* __restrict__ kvc,          // [12][4][8][16][16][128] bf16
  unsigned long long* __restrict__ xh,       // [2][8][16][128] u64
  unsigned long long* __restrict__ zA,       // [12][4][256][4] u64
  unsigned long long* __restrict__ zB,       // [12][4][256][4] u64
  int* __restrict__ flags,
  float* __restrict__ out)                   // [128][16][4]
{
  __shared__ float xf[16][260];
  __shared__ float zf[16][260];
  __shared__ float yf[16][260];
  __shared__ unsigned short xb[16][264];
  __shared__ unsigned short hs[16][264];
  __shared__ unsigned short qs[16][72];
  __shared__ unsigned short os[16][72];
  __shared__ __align__(16) unsigned short stg[8][4096];   // 8 waves x 8KB

  const int tid  = threadIdx.x;
  const int w    = tid >> 6, lane = tid & 63;
  const int l    = blockIdx.x >> 2;   // layer
  const int h    = blockIdx.x & 3;    // head / slice
  const int mrow = lane & 15, kgrp = lane >> 4;

  int* fin = flags;          // [12][4][8]
  int* fA  = flags + 384;    // [12][4]
  int* fB  = flags + 432;    // [12][4]

  const unsigned short* pQ  = wqkv + (size_t)(l*4 + h)*12*4096;
  const unsigned short* pWo = wo   + (size_t)(l*4 + h)*16*1024;
  const unsigned short* pL1 = wl1  + (size_t)(l*4 + h)*16*4096;
  const unsigned short* pL2 = wl2  + (size_t)(l*4 + h)*16*4096;
  unsigned short* sb = &stg[w][0];

  for (int t = 0; t < 16; ++t){
    for (int g = 0; g < 8; ++g){
      const int seq = t*8 + g + 1;

      // ===== input: wait upstream, read xh[l%2][g] =====
      {
        int need = (l == 0) ? t : (t+1);
        if (need > 0 && tid < 4){
          const int* fp = fin + (l*4 + tid)*8 + g;
          while (AL(fp) < need) __builtin_amdgcn_s_sleep(1);
        }
        __syncthreads();
        int row = tid >> 5, c8 = (tid & 31)*8;
        const unsigned long long* xp =
            xh + ((size_t)(l & 1)*8 + g)*2048 + (size_t)row*128 + (c8 >> 1);
        #pragma unroll
        for (int j = 0; j < 4; ++j){
          unsigned long long v = AL(xp + j);
          float f0 = lo_f(v), f1 = hi_f(v);
          xf[row][c8+2*j]   = f0;  xf[row][c8+2*j+1] = f1;
          xb[row][c8+2*j]   = f2b(f0);
          xb[row][c8+2*j+1] = f2b(f1);
        }
      }
      __syncthreads();

      // ===== QKV (head h): 12 tiles; waves 0-3 own {w, 8+w}, 4-7 own {w} ==
      {
        short8 a[8];
        #pragma unroll
        for (int kc = 0; kc < 8; ++kc)
          a[kc] = *(const short8*)&xb[mrow][kc*32 + kgrp*8];
        int nt = (w < 4) ? 2 : 1;
        for (int it = 0; it < nt; ++it){
          int tile = (it == 0) ? w : (8 + w);
          const unsigned short* src = pQ + (size_t)tile*4096;
          #pragma unroll
          for (int j = 0; j < 8; ++j)
            gload16(src + j*512 + lane*8, sb + j*512);
          WAIT_STG();
          f32x4 acc = {0,0,0,0};
          #pragma unroll
          for (int kc = 0; kc < 8; ++kc){
            short8 b0 = *(const short8*)(sb + kc*512 + lane*8);
            acc = __builtin_amdgcn_mfma_f32_16x16x32_bf16(a[kc], b0, acc, 0,0,0);
          }
          int p = tile >> 2, q4 = tile & 3;
          int n_l = q4*16 + mrow;
          float bias = bqkv[l*768 + p*256 + h*64 + n_l];
          #pragma unroll
          for (int r = 0; r < 4; ++r){
            int br = kgrp*4 + r;
            float v = acc[r] + bias;
            if (p == 0){
              qs[br][n_l] = f2b(v);
            } else {
              size_t kb = (((((size_t)l*4 + h)*8 + g)*16 + br)*16 + t)*128
                          + (p == 2 ? 64 : 0) + n_l;
              kvc[kb] = f2b(v);
            }
          }
          PIN_ORDER();
        }
      }
      __syncthreads();

      // ===== attention (head h, block-local KV) =====
      {
        int row = w*2 + (lane >> 5);
        int lid = lane & 31;
        float q0 = b2f(qs[row][lid*2]), q1 = b2f(qs[row][lid*2+1]);
        const unsigned short* base =
            kvc + (((((size_t)l*4 + h)*8 + g)*16 + row)*16)*128 + lid*2;
        float sv[16];
        #pragma unroll
        for (int j = 0; j < 16; ++j){
          if (j <= t){
            const unsigned short* kp = base + j*128;
            float p = q0*b2f(kp[0]) + q1*b2f(kp[1]);
            p += __shfl_xor(p, 1);
            p += __shfl_xor(p, 2);
            p += __shfl_xor(p, 4);
            p += __shfl_xor(p, 8);
            p += __shfl_xor(p, 16);
            sv[j] = p * 0.125f;
          } else sv[j] = -1e30f;
        }
        float mx = sv[0];
        #pragma unroll
        for (int j = 1; j < 16; ++j) mx = fmaxf(mx, sv[j]);
        float den = 0.f, e[16];
        #pragma unroll
        for (int j = 0; j < 16; ++j){ e[j] = __expf(sv[j]-mx); den += e[j]; }
        float rd = 1.f/den;
        float o0 = 0.f, o1 = 0.f;
        #pragma unroll
        for (int j = 0; j < 16; ++j){
          if (j <= t){
            const unsigned short* vp = base + j*128 + 64;
            o0 += e[j]*b2f(vp[0]);
            o1 += e[j]*b2f(vp[1]);
          }
        }
        os[row][lid*2]   = f2b(o0*rd);
        os[row][lid*2+1] = f2b(o1*rd);
      }
      __syncthreads();

      // ===== Wo K-split partial: tiles {2w, 2w+1}, staged together =====
      {
        short8 a2[2];
        #pragma unroll
        for (int kc = 0; kc < 2; ++kc)
          a2[kc] = *(const short8*)&os[mrow][kc*32 + kgrp*8];
        const unsigned short* src = pWo + (size_t)(w*2)*1024;
        #pragma unroll
        for (int j = 0; j < 4; ++j)
          gload16(src + j*512 + lane*8, sb + j*512);
        WAIT_STG();
        #pragma unroll
        for (int u2 = 0; u2 < 2; ++u2){
          int n_g = (w*2+u2)*16 + mrow;
          f32x4 acc = {0,0,0,0};
          #pragma unroll
          for (int kc = 0; kc < 2; ++kc){
            short8 b0 = *(const short8*)(sb + u2*1024 + kc*512 + lane*8);
            acc = __builtin_amdgcn_mfma_f32_16x16x32_bf16(a2[kc], b0, acc, 0,0,0);
          }
          AS(zA + ((size_t)(l*4 + h)*256 + n_g)*4 + kgrp, pack4b(acc));
        }
        PIN_ORDER();
      }
      PUBW(fA);

      // ===== sum zA -> zf (+bias +residual) =====
      {
        int col = tid & 255, rq2 = tid >> 8;
        float a8[8] = {0,0,0,0,0,0,0,0};
        #pragma unroll
        for (int s4 = 0; s4 < 4; ++s4){
          const unsigned long long* bp = zA + ((size_t)(l*4 + s4)*256 + col)*4 + rq2*2;
          #pragma unroll
          for (int q = 0; q < 2; ++q){
            unsigned long long v = AL(bp + q);
            a8[q*4+0] += b2f((unsigned short)v);
            a8[q*4+1] += b2f((unsigned short)(v >> 16));
            a8[q*4+2] += b2f((unsigned short)(v >> 32));
            a8[q*4+3] += b2f((unsigned short)(v >> 48));
          }
        }
        float bias = bo_[l*256 + col];
        #pragma unroll
        for (int r = 0; r < 8; ++r){
          int row = rq2*8 + r;
          zf[row][col] = a8[r] + bias + xf[row][col];
        }
      }
      __syncthreads();

      // ===== LN1 + cc + LN2 -> yf, xb =====
      {
        int row = tid >> 5, c8 = (tid & 31)*8;
        float tt[8];
        #pragma unroll
        for (int k = 0; k < 8; ++k) tt[k] = zf[row][c8+k];
        float sm = 0, sq = 0;
        #pragma unroll
        for (int k = 0; k < 8; ++k){ sm += tt[k]; sq += tt[k]*tt[k]; }
        sm += __shfl_xor(sm,1);  sq += __shfl_xor(sq,1);
        sm += __shfl_xor(sm,2);  sq += __shfl_xor(sq,2);
        sm += __shfl_xor(sm,4);  sq += __shfl_xor(sq,4);
        sm += __shfl_xor(sm,8);  sq += __shfl_xor(sq,8);
        sm += __shfl_xor(sm,16); sq += __shfl_xor(sq,16);
        float mean = sm*(1.f/256), var = sq*(1.f/256) - mean*mean;
        float rs = rsqrtf(var + EPS_);
        const float* g1p = g1 + l*256 + c8;
        const float* b1p = be1 + l*256 + c8;
        const unsigned short* ccp = cc + ((size_t)l*128 + g*16 + row)*256 + c8;
        #pragma unroll
        for (int k = 0; k < 8; ++k)
          tt[k] = (tt[k]-mean)*rs*g1p[k] + b1p[k] + b2f(ccp[k]);
        sm = 0; sq = 0;
        #pragma unroll
        for (int k = 0; k < 8; ++k){ sm += tt[k]; sq += tt[k]*tt[k]; }
        sm += __shfl_xor(sm,1);  sq += __shfl_xor(sq,1);
        sm += __shfl_xor(sm,2);  sq += __shfl_xor(sq,2);
        sm += __shfl_xor(sm,4);  sq += __shfl_xor(sq,4);
        sm += __shfl_xor(sm,8);  sq += __shfl_xor(sq,8);
        sm += __shfl_xor(sm,16); sq += __shfl_xor(sq,16);
        mean = sm*(1.f/256); var = sq*(1.f/256) - mean*mean;
        rs = rsqrtf(var + EPS_);
        const float* g2p = g2 + l*256 + c8;
        const float* b2p = be2 + l*256 + c8;
        #pragma unroll
        for (int k = 0; k < 8; ++k){
          float y = (tt[k]-mean)*rs*g2p[k] + b2p[k];
          yf[row][c8+k] = y;
          xb[row][c8+k] = f2b(y);
        }
      }
      __syncthreads();

      // ===== lin1: tiles {2w, 2w+1} serial (8KB buffer) + relu -> hs =====
      {
        short8 a[8];
        #pragma unroll
        for (int kc = 0; kc < 8; ++kc)
          a[kc] = *(const short8*)&xb[mrow][kc*32 + kgrp*8];
        for (int it = 0; it < 2; ++it){
          int tile = w*2 + it;
          const unsigned short* src = pL1 + (size_t)tile*4096;
          #pragma unroll
          for (int j = 0; j < 8; ++j)
            gload16(src + j*512 + lane*8, sb + j*512);
          WAIT_STG();
          f32x4 acc = {0,0,0,0};
          #pragma unroll
          for (int kc = 0; kc < 8; ++kc){
            short8 b0 = *(const short8*)(sb + kc*512 + lane*8);
            acc = __builtin_amdgcn_mfma_f32_16x16x32_bf16(a[kc], b0, acc, 0,0,0);
          }
          int n_sl = tile*16 + mrow;
          float bias = bl1[l*1024 + h*256 + n_sl];
          #pragma unroll
          for (int r = 0; r < 4; ++r){
            float hv = acc[r] + bias;
            hs[kgrp*4 + r][n_sl] = f2b(hv > 0.f ? hv : 0.f);
          }
          PIN_ORDER();
        }
      }
      __syncthreads();

      // ===== lin2: tiles {2w, 2w+1} serial -> zB =====
      {
        short8 ah[8];
        #pragma unroll
        for (int kc = 0; kc < 8; ++kc)
          ah[kc] = *(const short8*)&hs[mrow][kc*32 + kgrp*8];
        for (int it = 0; it < 2; ++it){
          int tile = w*2 + it;
          const unsigned short* src = pL2 + (size_t)tile*4096;
          #pragma unroll
          for (int j = 0; j < 8; ++j)
            gload16(src + j*512 + lane*8, sb + j*512);
          WAIT_STG();
          f32x4 acc = {0,0,0,0};
          #pragma unroll
          for (int kc = 0; kc < 8; ++kc){
            short8 b0 = *(const short8*)(sb + kc*512 + lane*8);
            acc = __builtin_amdgcn_mfma_f32_16x16x32_bf16(ah[kc], b0, acc, 0,0,0);
          }
          int n_g = tile*16 + mrow;
          AS(zB + ((size_t)(l*4 + h)*256 + n_g)*4 + kgrp, pack4b(acc));
          PIN_ORDER();
        }
      }
      PUBW(fB);

      // ===== sum zB -> zf (+bias +yf residual) =====
      {
        int col = tid & 255, rq2 = tid >> 8;
        float a8[8] = {0,0,0,0,0,0,0,0};
        #pragma unroll
        for (int s4 = 0; s4 < 4; ++s4){
          const unsigned long long* bp = zB + ((size_t)(l*4 + s4)*256 + col)*4 + rq2*2;
          #pragma unroll
          for (int q = 0; q < 2; ++q){
            unsigned long long v = AL(bp + q);
            a8[q*4+0] += b2f((unsigned short)v);
            a8[q*4+1] += b2f((unsigned short)(v >> 16));
            a8[q*4+2] += b2f((unsigned short)(v >> 32));
            a8[q*4+3] += b2f((unsigned short)(v >> 48));
          }
        }
        float bias = bl2[l*256 + col];
        #pragma unroll
        for (int r = 0; r < 8; ++r){
          int row = rq2*8 + r;
          zf[row][col] = a8[r] + bias + yf[row][col];
        }
      }
      __syncthreads();

      // ===== LN3 + handoff + fin post (+ head @ l==11) =====
      {
        int row = tid >> 5, c8 = (tid & 31)*8;
        float tt[8];
        #pragma unroll
        for (int k = 0; k < 8; ++k) tt[k] = zf[row][c8+k];
        float sm = 0, sq = 0;
        #pragma unroll
        for (int k = 0; k < 8; ++k){ sm += tt[k]; sq += tt[k]*tt[k]; }
        sm += __shfl_xor(sm,1);  sq += __shfl_xor(sq,1);
        sm += __shfl_xor(sm,2);  sq += __shfl_xor(sq,2);
        sm += __shfl_xor(sm,4);  sq += __shfl_xor(sq,4);
        sm += __shfl_xor(sm,8);  sq += __shfl_xor(sq,8);
        sm += __shfl_xor(sm,16); sq += __shfl_xor(sq,16);
        float mean = sm*(1.f/256), var = sq*(1.f/256) - mean*mean;
        float rs = rsqrtf(var + EPS_);
        const float* g3p = g3 + l*256 + c8;
        const float* b3p = be3 + l*256 + c8;
        float xn[8];
        #pragma unroll
        for (int k = 0; k < 8; ++k)
          xn[k] = (tt[k]-mean)*rs*g3p[k] + b3p[k];

        float pr[4] = {0,0,0,0};
        const bool doHead = (l == 11) && (h == 0);
        if (doHead){
          #pragma unroll
          for (int p = 0; p < 4; ++p){
            float a = 0.f;
            #pragma unroll
            for (int k = 0; k < 8; ++k) a += xn[k]*outW[p*256 + c8 + k];
            a += __shfl_xor(a,1); a += __shfl_xor(a,2);
            a += __shfl_xor(a,4); a += __shfl_xor(a,8);
            a += __shfl_xor(a,16);
            pr[p] = a;
          }
        }
        if (l == 11 && t < 15){
          const float* pp = pos + (t+1)*256 + c8;
          #pragma unroll
          for (int k = 0; k < 8; ++k) xn[k] += pp[k];
        }
        const bool last = (l == 11) && (t == 15);
        if (!last && ((c8 >> 6) == h)){
          unsigned long long* xp =
              xh + ((size_t)((l+1) & 1)*8 + g)*2048 + (size_t)row*128 + (c8 >> 1);
          #pragma unroll
          for (int j = 0; j < 4; ++j)
            AS(xp + j, pack2f(xn[2*j], xn[2*j+1]));
        }
        __syncthreads();
        if (!last && tid == 0)
          AS(fin + (((l+1) % 12)*4 + h)*8 + g, t+1);
        if (doHead && ((tid & 31) == 0)){
          int gr = g*16 + row;
          #pragma unroll
          for (int p = 0; p < 4; ++p){
            float v2 = pr[p] + outb[p];
            float sg = 1.f/(1.f + __expf(-v2));
            out[((size_t)gr*16 + t)*4 + p] = plow[p] + (phigh[p]-plow[p])*sg;
          }
        }
      }
    }
  }
}

extern "C" void kernel_launch(void* const* d_in, const int* in_sizes, int n_in,
                              void* d_out, int out_size, void* d_ws, size_t ws_size,
                              hipStream_t stream) {
  const float* U_real = (const float*)d_in[0];
  const float* U_imag = (const float*)d_in[1];
  const float* tok_W  = (const float*)d_in[2];
  const float* tok_b  = (const float*)d_in[3];
  const float* pos    = (const float*)d_in[4];
  const float* saW    = (const float*)d_in[5];
  const float* sab    = (const float*)d_in[6];
  const float* saWo   = (const float*)d_in[7];
  const float* sabo   = (const float*)d_in[8];
  const float* caW    = (const float*)d_in[9];
  const float* cab    = (const float*)d_in[10];
  const float* caWo   = (const float*)d_in[11];
  const float* cabo   = (const float*)d_in[12];
  const float* l1W    = (const float*)d_in[13];
  const float* l1b    = (const float*)d_in[14];
  const float* l2W    = (const float*)d_in[15];
  const float* l2b    = (const float*)d_in[16];
  const float* g1     = (const float*)d_in[17];
  const float* be1    = (const float*)d_in[18];
  const float* g2     = (const float*)d_in[19];
  const float* be2    = (const float*)d_in[20];
  const float* g3     = (const float*)d_in[21];
  const float* be3    = (const float*)d_in[22];
  const float* outW   = (const float*)d_in[23];
  const float* outb   = (const float*)d_in[24];
  const float* plow   = (const float*)d_in[25];
  const float* phigh  = (const float*)d_in[26];

  char* ws = (char*)d_ws;
  unsigned short* wb        = (unsigned short*)(ws + OFF_WQKV);
  float* srcb               = (float*)(ws + OFF_SRC);
  unsigned short* ccb       = (unsigned short*)(ws + OFF_CC);
  unsigned short* kvc       = (unsigned short*)(ws + OFF_KV);
  unsigned long long* xhb   = (unsigned long long*)(ws + OFF_XH);
  unsigned long long* zAb   = (unsigned long long*)(ws + OFF_ZA);
  unsigned long long* zBb   = (unsigned long long*)(ws + OFF_ZB);
  int* flags                = (int*)(ws + OFF_FLG);

  (void)hipMemsetAsync(ws + OFF_FLG, 0, 4096, stream);
  k_conv<<<dim3(4608), dim3(256), 0, stream>>>(saW, saWo, l1W, l2W, wb);
  k_src<<<dim3(128), dim3(256), 0, stream>>>(U_real, U_imag, tok_W, tok_b, pos,
                                             srcb, (float*)xhb);
  k_cc<<<dim3(1536), dim3(256), 0, stream>>>(caW, cab, caWo, cabo, srcb, ccb);
  k_main<<<dim3(48), dim3(512), 0, stream>>>(
      wb,
      (unsigned short*)(ws + OFF_WO),
      (unsigned short*)(ws + OFF_L1),
      (unsigned short*)(ws + OFF_L2),
      sab, sabo, l1b, l2b,
      g1, be1, g2, be2, g3, be3,
      ccb, pos, outW, outb, plow, phigh,
      kvc, xhb, zAb, zBb, flags, (float*)d_out);
}